// Round 1
// 603.932 us; speedup vs baseline: 1.1450x; 1.1450x over previous
//
#include <hip/hip_runtime.h>

// ---------- types / helpers ----------
typedef unsigned short u16;
typedef unsigned int   u32;
typedef __attribute__((ext_vector_type(4))) float  f32x4;
typedef __attribute__((ext_vector_type(8))) __bf16 bf16x8;
typedef __attribute__((ext_vector_type(8))) u16    u16x8;
typedef __attribute__((address_space(1))) void as1_void;
typedef __attribute__((address_space(3))) void as3_void;

// compaction lists (module-scope device globals; rewritten fully every launch)
__device__ int g_idx0[2048];
__device__ int g_idx1[2048];
__device__ int g_cnt[2];

__device__ __forceinline__ void async16(const void* g, void* l) {
  // global -> LDS direct copy, 16 B per lane; LDS dest = wave-uniform base + lane*16
  __builtin_amdgcn_global_load_lds((const as1_void*)g, (as3_void*)l, 16, 0, 0);
}

__device__ __forceinline__ u16 f2bf(float f) {
  u32 u = __builtin_bit_cast(u32, f);
  return (u16)((u + 0x7fffu + ((u >> 16) & 1u)) >> 16);  // RNE
}

// ---------- 128x128-tile bf16 MFMA GEMM core (m97 structure), per-block ----------
// MODE 0: A linear, C fp32 rows=bm..bm+127, cols colOff+[0,Nreal)
// MODE 1: A rows gathered via idx[slot], C bf16 compact (row=slot, ld=ldc), no col guard
// MODE 2: A linear (compact), C fp32 scatter rows idx[slot] (slot<cnt), cols colOff+[0,Nreal)
template <int MODE>
__device__ __forceinline__ void gemm_core(
    u16* As, u16* Bs,
    const u16* __restrict__ A, const u16* __restrict__ Bt,
    void* __restrict__ Cout, int K, int ldc, int colOff, int Nreal,
    const int* __restrict__ idx, int cnt, int bm, int bn)
{
  const int tid  = threadIdx.x;
  const int wid  = tid >> 6;
  const int lane = tid & 63;
  const int quad = lane >> 4;
  const int l16  = lane & 15;
  const int wm = (wid >> 1) * 64;
  const int wn = (wid & 1) * 64;

  f32x4 acc[4][4] = {};

  // staging map: lane -> (row, 8-elem chunk); wave w stages 1 KB at base w*1KB (+2048 elems for row+64)
  const int srow = wid * 16 + (lane >> 2);
  const int scol = (lane & 3) * 8;

  size_t ar0, ar1;
  if (MODE == 1) { ar0 = (size_t)idx[bm + srow]; ar1 = (size_t)idx[bm + srow + 64]; }
  else           { ar0 = (size_t)(bm + srow);    ar1 = ar0 + 64; }
  const u16* ga0 = A + ar0 * K + scol;
  const u16* ga1 = A + ar1 * K + scol;
  const u16* gb0 = Bt + (size_t)(bn + srow) * K + scol;
  const u16* gb1 = gb0 + (size_t)64 * K;

  for (int k0 = 0; k0 < K; k0 += 32) {
    async16(ga0 + k0, As + wid * 512);
    async16(ga1 + k0, As + wid * 512 + 2048);
    async16(gb0 + k0, Bs + wid * 512);
    async16(gb1 + k0, Bs + wid * 512 + 2048);
    __syncthreads();

    bf16x8 af[4], bfr[4];
#pragma unroll
    for (int i = 0; i < 4; i++) {
      af[i]  = *reinterpret_cast<const bf16x8*>(As + (wm + i * 16 + l16) * 32 + quad * 8);
      bfr[i] = *reinterpret_cast<const bf16x8*>(Bs + (wn + i * 16 + l16) * 32 + quad * 8);
    }
#pragma unroll
    for (int mi = 0; mi < 4; mi++)
#pragma unroll
      for (int ni = 0; ni < 4; ni++)
        acc[mi][ni] = __builtin_amdgcn_mfma_f32_16x16x32_bf16(af[mi], bfr[ni], acc[mi][ni], 0, 0, 0);
    __syncthreads();
  }

  // epilogue: C/D layout col = lane&15, row = quad*4 + reg  [m89/m91 verified]
#pragma unroll
  for (int mi = 0; mi < 4; mi++) {
    const int rbase = bm + wm + mi * 16 + quad * 4;
    int  orow[4];
    bool vld[4];
#pragma unroll
    for (int r = 0; r < 4; r++) {
      if (MODE == 2) {
        int slot = rbase + r;
        vld[r]  = slot < cnt;
        orow[r] = vld[r] ? idx[slot] : 0;
      } else {
        vld[r] = true; orow[r] = rbase + r;
      }
    }
#pragma unroll
    for (int ni = 0; ni < 4; ni++) {
      const int col = bn + wn + ni * 16 + l16;
      if (MODE == 1) {
        u16* C = (u16*)Cout;
#pragma unroll
        for (int r = 0; r < 4; r++)
          C[(size_t)orow[r] * ldc + col] = f2bf(acc[mi][ni][r]);
      } else {
        if (col < Nreal) {
          float* C = (float*)Cout;
#pragma unroll
          for (int r = 0; r < 4; r++)
            if (vld[r]) C[(size_t)orow[r] * ldc + colOff + col] = acc[mi][ni][r];
        }
      }
    }
  }
}

// ---------- fp32 (K,N) -> bf16 (Npad,K) transpose-convert tile, zero-pad n>=N ----------
__device__ __forceinline__ void tconv_core(float (*tile)[33], const float* __restrict__ in,
                                           u16* __restrict__ out, int K, int N, int bx, int by) {
  int tx = threadIdx.x & 31, ty = threadIdx.x >> 5;
  int n0 = bx * 32, k0 = by * 32;
#pragma unroll
  for (int i = 0; i < 4; i++) {
    int k = k0 + ty + i * 8;
    int n = n0 + tx;
    tile[ty + i * 8][tx] = (n < N) ? in[(size_t)k * N + n] : 0.0f;
  }
  __syncthreads();
#pragma unroll
  for (int i = 0; i < 4; i++)
    out[(size_t)(n0 + ty + i * 8) * K + k0 + tx] = f2bf(tile[tx][ty + i * 8]);
}

// ---------- fused prep: all conversions + row-compaction list build, one launch ----------
// blocks: [0,1024) cvt hidden | [1024,3072) head_w | [3072,4096) down0 |
//         [4096,12160) dec0 | [12160,12416) down1 | [12416,22432) dec1 | 22432 build idx
__global__ __launch_bounds__(256) void prep(
    const float* __restrict__ hidden, const int* __restrict__ target,
    const float* __restrict__ head_w, const float* __restrict__ down0,
    const float* __restrict__ dec0, const float* __restrict__ down1,
    const float* __restrict__ dec1,
    u16* __restrict__ hA, u16* __restrict__ head_wT, u16* __restrict__ down0T,
    u16* __restrict__ dec0T, u16* __restrict__ down1T, u16* __restrict__ dec1T)
{
  __shared__ float tile[32][33];
  __shared__ int cc[2];
  const int b = blockIdx.x;
  const int tid = threadIdx.x;
  if (b < 1024) {
    int i = b * 256 + tid;  // 262144 u16x8 chunks total
    const float4* p = reinterpret_cast<const float4*>(hidden) + (size_t)i * 2;
    float4 a = p[0], c = p[1];
    u16x8 o;
    o[0] = f2bf(a.x); o[1] = f2bf(a.y); o[2] = f2bf(a.z); o[3] = f2bf(a.w);
    o[4] = f2bf(c.x); o[5] = f2bf(c.y); o[6] = f2bf(c.z); o[7] = f2bf(c.w);
    reinterpret_cast<u16x8*>(hA)[i] = o;
  } else if (b < 3072) {
    int r = b - 1024;  tconv_core(tile, head_w, head_wT, 1024, 2002,  r % 64,   r / 64);
  } else if (b < 4096) {
    int r = b - 3072;  tconv_core(tile, down0,  down0T,  1024, 1024,  r % 32,   r / 32);
  } else if (b < 12160) {
    int r = b - 4096;  tconv_core(tile, dec0,   dec0T,   1024, 8000,  r % 252,  r / 252);
  } else if (b < 12416) {
    int r = b - 12160; tconv_core(tile, down1,  down1T,  1024, 256,   r % 8,    r / 8);
  } else if (b < 22432) {
    int r = b - 12416; tconv_core(tile, dec1,   dec1T,   256,  40000, r % 1252, r / 1252);
  } else {
    // build compaction lists: cluster0 = [2000,10000), cluster1 = [10000,50000)
    if (tid < 2) cc[tid] = 0;
    __syncthreads();
    for (int i = tid; i < 2048; i += 256) {
      int t = target[i];
      if (t >= 2000 && t < 10000)  g_idx0[atomicAdd(&cc[0], 1)] = i;
      else if (t >= 10000)         g_idx1[atomicAdd(&cc[1], 1)] = i;
    }
    __syncthreads();
    int n0 = cc[0], n1 = cc[1];
    for (int i = tid; i < 2048; i += 256) {  // pad with row 0 (staged but never stored)
      if (i >= n0) g_idx0[i] = 0;
      if (i >= n1) g_idx1[i] = 0;
    }
    if (tid == 0) { g_cnt[0] = n0; g_cnt[1] = n1; }
  }
}

// ---------- GEMM wave 1: head (full M) + compacted down-projections X0c/X1c ----------
// blocks: [0,256) head 16x16 | [256,384) X0c 16row x 8col | [384,416) X1c 16row x 2col
__global__ __launch_bounds__(256, 2) void g1(
    const u16* __restrict__ hA, const u16* __restrict__ head_wT,
    const u16* __restrict__ down0T, const u16* __restrict__ down1T,
    u16* __restrict__ X0c, u16* __restrict__ X1c, float* __restrict__ out)
{
  __shared__ u16 As[4096], Bs[4096];
  const int b = blockIdx.x;
  if (b < 256) {
    gemm_core<0>(As, Bs, hA, head_wT, out, 1024, 50002, 0, 2002,
                 nullptr, 2048, (b >> 4) * 128, (b & 15) * 128);
  } else if (b < 384) {
    int r = b - 256, bm = (r & 15) * 128, bn = (r >> 4) * 128;
    if (bm < g_cnt[0])
      gemm_core<1>(As, Bs, hA, down0T, X0c, 1024, 1024, 0, 1024, g_idx0, g_cnt[0], bm, bn);
  } else {
    int r = b - 384, bm = (r & 15) * 128, bn = (r >> 4) * 128;
    if (bm < g_cnt[1])
      gemm_core<1>(As, Bs, hA, down1T, X1c, 1024, 256, 0, 256, g_idx1, g_cnt[1], bm, bn);
  }
}

// ---------- GEMM wave 2: compacted tail decodes (scatter) + zero-fill inactive rows ----------
// blocks: [0,1008) tail0 16row x 63col | [1008,6016) tail1 16row x 313col | [6016,8064) fill
__global__ __launch_bounds__(256, 2) void g2(
    const u16* __restrict__ X0c, const u16* __restrict__ X1c,
    const u16* __restrict__ dec0T, const u16* __restrict__ dec1T,
    const int* __restrict__ target, float* __restrict__ out)
{
  __shared__ u16 As[4096], Bs[4096];
  const int b = blockIdx.x;
  if (b < 1008) {
    int bm = (b & 15) * 128, bn = (b >> 4) * 128;
    if (bm < g_cnt[0])
      gemm_core<2>(As, Bs, X0c, dec0T, out, 1024, 50002, 2002, 8000, g_idx0, g_cnt[0], bm, bn);
  } else if (b < 6016) {
    int r = b - 1008, bm = (r & 15) * 128, bn = (r >> 4) * 128;
    if (bm < g_cnt[1])
      gemm_core<2>(As, Bs, X1c, dec1T, out, 256, 50002, 10002, 40000, g_idx1, g_cnt[1], bm, bn);
  } else {
    // one block per row: zero the tail regions this row does NOT belong to.
    // col ranges are even -> float2 (8 B) aligned everywhere.
    int row = b - 6016;
    int t = target[row];
    bool in0 = (t >= 2000) && (t < 10000);
    bool in1 = (t >= 10000);
    float2* p = reinterpret_cast<float2*>(out + (size_t)row * 50002);
    float2 z; z.x = 0.0f; z.y = 0.0f;
    if (!in0)
      for (int i = threadIdx.x; i < 4000; i += 256)  p[1001 + i] = z;   // cols [2002,10002)
    if (!in1)
      for (int i = threadIdx.x; i < 20000; i += 256) p[5001 + i] = z;   // cols [10002,50002)
  }
}

// ---------- launch ----------
extern "C" void kernel_launch(void* const* d_in, const int* in_sizes, int n_in,
                              void* d_out, int out_size, void* d_ws, size_t ws_size,
                              hipStream_t stream) {
  const float* hidden = (const float*)d_in[0];  // (2048,1024)
  const int*   target = (const int*)d_in[1];    // (2048,)
  const float* head_w = (const float*)d_in[2];  // (1024,2002)
  const float* down0  = (const float*)d_in[3];  // (1024,1024)
  const float* dec0   = (const float*)d_in[4];  // (1024,8000)
  const float* down1  = (const float*)d_in[5];  // (1024,256)
  const float* dec1   = (const float*)d_in[6];  // (256,40000)
  float* out = (float*)d_out;                   // (2048,50002)

  // workspace layout (bf16), unchanged from previous session; idx lives in __device__ globals
  char* ws = (char*)d_ws;
  const size_t NEED = 53280768;
  if (ws_size < NEED) return;  // visible failure instead of corruption
  u16* hA      = (u16*)(ws);                 // 2048x1024
  u16* head_wT = (u16*)(ws + 4194304);       // 2048x1024 (padded from 2002)
  u16* down0T  = (u16*)(ws + 8388608);       // 1024x1024
  u16* dec0T   = (u16*)(ws + 10485760);      // 8064x1024 (padded from 8000)
  u16* down1T  = (u16*)(ws + 27000832);      // 256x1024
  u16* dec1T   = (u16*)(ws + 27525120);      // 40064x256 (padded from 40000)
  u16* X0c     = (u16*)(ws + 48037888);      // up to 2048x1024 (compact rows)
  u16* X1c     = (u16*)(ws + 52232192);      // up to 2048x256  (compact rows)

  prep<<<22433, 256, 0, stream>>>(hidden, target, head_w, down0, dec0, down1, dec1,
                                  hA, head_wT, down0T, dec0T, down1T, dec1T);
  g1<<<416, 256, 0, stream>>>(hA, head_wT, down0T, down1T, X0c, X1c, out);
  g2<<<8064, 256, 0, stream>>>(X0c, X1c, dec0T, dec1T, target, out);
}